// Round 8
// baseline (471.836 us; speedup 1.0000x reference)
//
#include <hip/hip_runtime.h>
#include <hip/hip_fp16.h>

#define BATCH   4
#define SEQ     2048
#define DM      1024
#define HEADS   16
#define HD      64
#define M_TOK   (BATCH * SEQ)   // 8192
#define QK_LD   2048            // merged Q|K projection leading dim

// 0.125 (1/sqrt(64)) * log2(e): folded into Wq so logits come out in log2 units.
#define QSCALE  0.1803368801111204f

typedef __attribute__((ext_vector_type(8)))  _Float16 half8;
typedef __attribute__((ext_vector_type(4)))  float    f32x4;
typedef __attribute__((ext_vector_type(16))) float    f32x16;

__device__ __forceinline__ unsigned short f2h(float x) {
    return __half_as_ushort(__float2half(x));
}
__device__ __forceinline__ float h2f(unsigned short u) {
    return __half2float(__ushort_as_half(u));
}
// exp2 on the trans unit. Builtin (NOT volatile asm) so the scheduler can
// interleave it with MFMA issue -- R7's asm volatile pinned the order.
#if __has_builtin(__builtin_amdgcn_exp2f)
#define EXP2F(x) __builtin_amdgcn_exp2f(x)
#else
__device__ __forceinline__ float exp2_asm(float x) {
    float r; asm("v_exp_f32 %0, %1" : "=v"(r) : "v"(x)); return r;
}
#define EXP2F(x) exp2_asm(x)
#endif
// pack two f32 -> f16x2 in one VGPR (v_cvt_pkrtz_f16_f32), a in [15:0].
__device__ __forceinline__ unsigned int pk2(float a, float b) {
    __fp16 __attribute__((ext_vector_type(2))) h =
        __builtin_amdgcn_cvt_pkrtz(a, b);
    return __builtin_bit_cast(unsigned int, h);
}
// async global->LDS DMA, 16B per lane; LDS dest = uniform base + lane*16.
__device__ __forceinline__ void dma16(const void* g, void* l) {
    __builtin_amdgcn_global_load_lds(
        (const __attribute__((address_space(1))) void*)g,
        (__attribute__((address_space(3))) void*)l, 16, 0, 0);
}

// ---------------------------------------------------------------------------
// x -> hi/lo f16 split (elementwise)
// ---------------------------------------------------------------------------
__global__ __launch_bounds__(256) void split_cast(
    const float* __restrict__ x, unsigned short* __restrict__ hi,
    unsigned short* __restrict__ lo)
{
    const int i = (blockIdx.x * 256 + threadIdx.x) * 8;
    float4 a = *(const float4*)(x + i);
    float4 b = *(const float4*)(x + i + 4);
    float v[8] = {a.x, a.y, a.z, a.w, b.x, b.y, b.z, b.w};
    unsigned short hb[8], lb[8];
#pragma unroll
    for (int j = 0; j < 8; ++j) {
        hb[j] = f2h(v[j]);
        lb[j] = f2h(v[j] - h2f(hb[j]));
    }
    *(float4*)(hi + i) = *(float4*)hb;
    *(float4*)(lo + i) = *(float4*)lb;
}

// ---------------------------------------------------------------------------
// All 4 weight transposes in ONE dispatch (grid.z selects the weight).
// W[K][N] f32 -> Wt[N][K] f16 (+scale, +split for z<2).
// ---------------------------------------------------------------------------
__global__ __launch_bounds__(256) void wtrans_all(
    const float* __restrict__ Wq, const float* __restrict__ Wk,
    const float* __restrict__ Wv, const float* __restrict__ Wo,
    unsigned short* __restrict__ Wqkt_h, unsigned short* __restrict__ Wqkt_l,
    unsigned short* __restrict__ Wvt, unsigned short* __restrict__ Wot)
{
    __shared__ unsigned short Th[64][72];
    __shared__ unsigned short Tl[64][72];
    const int z = blockIdx.z;
    const float* W = (z == 0) ? Wq : (z == 1) ? Wk : (z == 2) ? Wv : Wo;
    unsigned short* Th_out = (z == 0) ? Wqkt_h
                           : (z == 1) ? Wqkt_h + (size_t)DM * DM
                           : (z == 2) ? Wvt : Wot;
    unsigned short* Tl_out = (z == 0) ? Wqkt_l : Wqkt_l + (size_t)DM * DM;
    const float scale = (z == 0) ? QSCALE : 1.0f;
    const bool split = (z < 2);

    const int t  = threadIdx.x;
    const int n0 = blockIdx.x * 64, k0 = blockIdx.y * 64;
    const int kr = t >> 2, cg = (t & 3) << 4;
#pragma unroll
    for (int jj = 0; jj < 16; jj += 4) {
        float4 wv = *(const float4*)(W + (size_t)(k0 + kr) * DM + n0 + cg + jj);
        float vv[4] = {wv.x, wv.y, wv.z, wv.w};
#pragma unroll
        for (int j = 0; j < 4; ++j) {
            float v = vv[j] * scale;
            unsigned short h = f2h(v);
            Th[cg + jj + j][kr] = h;
            Tl[cg + jj + j][kr] = f2h(v - h2f(h));
        }
    }
    __syncthreads();
    const int nr = t >> 2, kg = (t & 3) << 4;
    size_t go = (size_t)(n0 + nr) * DM + k0 + kg;
    *(float4*)(Th_out + go)     = *(float4*)&Th[nr][kg];
    *(float4*)(Th_out + go + 8) = *(float4*)&Th[nr][kg + 8];
    if (split) {
        *(float4*)(Tl_out + go)     = *(float4*)&Tl[nr][kg];
        *(float4*)(Tl_out + go + 8) = *(float4*)&Tl[nr][kg + 8];
    }
}

// ---------------------------------------------------------------------------
// 3-pass split QK projection GEMM, 32x32x16 MFMA, BK=16, 3 waves/SIMD.
// C[M_TOK, QK_LD] = A @ Bt^T with A,B split hi/lo (hh + hl + lh passes).
// LDS: 2 bufs x 4 arrays x [128][16] f16 (4 KB) = 32 KB; wave w stages array w.
// XOR swizzle: LDS[row][c] = g[row][c ^ ((row>>2)&1)] (2 chunks/row) so both
// the lane-contiguous DMA dest and the frag reads are conflict-free.
// Output: split f16 (Oh, Ol). Double-buffered, one barrier per iter.
// ---------------------------------------------------------------------------
__global__ __launch_bounds__(256, 3) void gemm_qk(
    const unsigned short* __restrict__ Ah, const unsigned short* __restrict__ Al,
    const unsigned short* __restrict__ Bh, const unsigned short* __restrict__ Bl,
    unsigned short* __restrict__ Oh, unsigned short* __restrict__ Ol)
{
    __shared__ unsigned short SM[2][4][128 * 16];

    const int t = threadIdx.x;
    const int w = t >> 6, lane = t & 63;
    const int g = lane >> 5, l31 = lane & 31;
    const int wm = w >> 1, wn = w & 1;
    const int m0 = blockIdx.y * 128, n0 = blockIdx.x * 128;

    // DMA: wave w stages its array; 4 insts x 32 rows x 2 chunks.
    const unsigned short* src = (w == 0) ? Ah : (w == 1) ? Bh : (w == 2) ? Al : Bl;
    const int base0 = (w == 1 || w == 3) ? n0 : m0;
    const int drl = lane >> 1;                        // row in 32-row group
    const int dch = (lane & 1) ^ ((lane >> 3) & 1);   // swizzled source chunk

    auto stage = [&](int buf, int k0) {
#pragma unroll
        for (int i = 0; i < 4; ++i) {
            const int row = i * 32 + drl;
            dma16(src + (size_t)(base0 + row) * DM + k0 + dch * 8,
                  &SM[buf][w][i * 32 * 16]);
        }
    };

    f32x16 acc[2][2];
#pragma unroll
    for (int mt = 0; mt < 2; ++mt)
#pragma unroll
        for (int nt = 0; nt < 2; ++nt)
#pragma unroll
            for (int r = 0; r < 16; ++r) acc[mt][nt][r] = 0.f;

    stage(0, 0);
    const int NIT = DM / 16;
    for (int it = 0; it < NIT; ++it) {
        __syncthreads();
        const int cur = it & 1;
        if (it + 1 < NIT) stage(cur ^ 1, (it + 1) * 16);

        half8 a_h[2], b_h[2], a_l[2], b_l[2];
#pragma unroll
        for (int mt = 0; mt < 2; ++mt) {
            const int row = wm * 64 + mt * 32 + l31;
            const int off = row * 16 + ((g ^ ((l31 >> 2) & 1)) * 8);
            a_h[mt] = *(const half8*)&SM[cur][0][off];
            a_l[mt] = *(const half8*)&SM[cur][2][off];
        }
#pragma unroll
        for (int nt = 0; nt < 2; ++nt) {
            const int row = wn * 64 + nt * 32 + l31;
            const int off = row * 16 + ((g ^ ((l31 >> 2) & 1)) * 8);
            b_h[nt] = *(const half8*)&SM[cur][1][off];
            b_l[nt] = *(const half8*)&SM[cur][3][off];
        }
#pragma unroll
        for (int mt = 0; mt < 2; ++mt)
#pragma unroll
            for (int nt = 0; nt < 2; ++nt) {
                acc[mt][nt] = __builtin_amdgcn_mfma_f32_32x32x16_f16(
                    a_h[mt], b_h[nt], acc[mt][nt], 0, 0, 0);
                acc[mt][nt] = __builtin_amdgcn_mfma_f32_32x32x16_f16(
                    a_h[mt], b_l[nt], acc[mt][nt], 0, 0, 0);
                acc[mt][nt] = __builtin_amdgcn_mfma_f32_32x32x16_f16(
                    a_l[mt], b_h[nt], acc[mt][nt], 0, 0, 0);
            }
    }

    // Epilogue: 32x32 C/D layout: col = lane&31, row = (r&3)+8*(r>>2)+4g.
#pragma unroll
    for (int mt = 0; mt < 2; ++mt)
#pragma unroll
        for (int nt = 0; nt < 2; ++nt) {
            const int col = n0 + wn * 64 + nt * 32 + l31;
#pragma unroll
            for (int r = 0; r < 16; ++r) {
                const int row = m0 + wm * 64 + mt * 32 +
                                (r & 3) + 8 * (r >> 2) + 4 * g;
                const float v = acc[mt][nt][r];
                const unsigned short h = f2h(v);
                Oh[(size_t)row * QK_LD + col] = h;
                Ol[(size_t)row * QK_LD + col] = f2h(v - h2f(h));
            }
        }
}

// ---------------------------------------------------------------------------
// f16 MFMA GEMM (1-pass), m97+dbuf: C = A[M,K] @ Bt[N,K]^T, 128x128, BK=32.
// EPI: 0 = f32 out; 3 = per-head-transposed f16 V (O0 = Vt[b][h][d][s]).
// ---------------------------------------------------------------------------
template<int EPI>
__global__ __launch_bounds__(256, 3) void gemm_f16(
    const unsigned short* __restrict__ Ah, const unsigned short* __restrict__ Bh,
    void* __restrict__ O0, int M, int N, int K)
{
    __shared__ unsigned short As_h[2][128 * 32];
    __shared__ unsigned short Bs_h[2][128 * 32];

    const int t = threadIdx.x;
    const int w = t >> 6, lane = t & 63, quad = lane >> 4, l15 = lane & 15;
    const int wm = w >> 1, wn = w & 1;
    const int m0 = blockIdx.y * 128, n0 = blockIdx.x * 128;

    const int drow = w * 32 + (lane >> 2);
    const int dcol = (lane & 3) * 8;

    auto stage = [&](int buf, int k0) {
#pragma unroll
        for (int inst = 0; inst < 2; ++inst) {
            const size_t ga = (size_t)(m0 + drow + inst * 16) * K + k0 + dcol;
            const size_t gb = (size_t)(n0 + drow + inst * 16) * K + k0 + dcol;
            const int lo = (w * 32 + inst * 16) * 32;
            dma16(Ah + ga, &As_h[buf][lo]);
            dma16(Bh + gb, &Bs_h[buf][lo]);
        }
    };

    f32x4 acc[4][4];
#pragma unroll
    for (int mt = 0; mt < 4; ++mt)
#pragma unroll
        for (int nt = 0; nt < 4; ++nt)
#pragma unroll
            for (int r = 0; r < 4; ++r) acc[mt][nt][r] = 0.f;

    const int NIT = K >> 5;
    stage(0, 0);
    for (int it = 0; it < NIT; ++it) {
        __syncthreads();
        const int cur = it & 1;
        if (it + 1 < NIT) stage(cur ^ 1, (it + 1) * 32);

        half8 aH[4], bH[4];
#pragma unroll
        for (int mt = 0; mt < 4; ++mt)
            aH[mt] = *(const half8*)&As_h[cur][(wm * 64 + mt * 16 + l15) * 32 + quad * 8];
#pragma unroll
        for (int nt = 0; nt < 4; ++nt)
            bH[nt] = *(const half8*)&Bs_h[cur][(wn * 64 + nt * 16 + l15) * 32 + quad * 8];
#pragma unroll
        for (int mt = 0; mt < 4; ++mt)
#pragma unroll
            for (int nt = 0; nt < 4; ++nt)
                acc[mt][nt] = __builtin_amdgcn_mfma_f32_16x16x32_f16(
                    aH[mt], bH[nt], acc[mt][nt], 0, 0, 0);
    }

    // Epilogue. C/D layout: col = lane&15, row = quad*4 + reg.
#pragma unroll
    for (int mt = 0; mt < 4; ++mt)
#pragma unroll
        for (int nt = 0; nt < 4; ++nt) {
            const int row0 = m0 + wm * 64 + mt * 16 + quad * 4;
            const int col  = n0 + wn * 64 + nt * 16 + l15;
            if (EPI == 0) {
#pragma unroll
                for (int r = 0; r < 4; ++r)
                    ((float*)O0)[(size_t)(row0 + r) * N + col] = acc[mt][nt][r];
            } else {  // EPI == 3: Vt[b][h][d][s]; regs are consecutive s
                const int b = row0 >> 11, s = row0 & 2047;
                const int hh = col >> 6, d = col & 63;
                unsigned short vs[4];
#pragma unroll
                for (int r = 0; r < 4; ++r) vs[r] = f2h(acc[mt][nt][r]);
                *(ushort4*)((unsigned short*)O0 +
                            (((size_t)(b * HEADS + hh)) * HD + d) * SEQ + s) =
                    *(ushort4*)vs;
            }
        }
}

// ---------------------------------------------------------------------------
// 32x32x16 MFMA flash attention, async-pipelined + phase-staggered.
// Grid (bh=64, qtile=8): blocks sharing (b,h) K/V differ by 64 = 0 mod 8 ->
// SAME XCD -> L2 reuse (R7's qtile-major grid spread them over all 8 XCDs).
// Block = 256-row Q tile, 4 waves x 2 q-sets. Per iter: S(qs0), S(qs1) MFMAs
// issued; then softmax0+P0 (VALU) -> PV0 (matrix) -> softmax1+P1 (VALU,
// overlaps PV0) -> PV1. Quiet-iter fast path (ballot on new max) skips the
// alpha-rescale when no lane saw a new running max.
// ---------------------------------------------------------------------------
__global__ __launch_bounds__(256, 2) void attn_f16(
    const unsigned short* __restrict__ QKh,   // [M_TOK][2048]: Q | K  (hi)
    const unsigned short* __restrict__ QKl,   // [M_TOK][2048]: Q | K  (lo)
    const unsigned short* __restrict__ Vt,    // [b][h][d][s]
    unsigned short* __restrict__ Oc)          // [b][s][h*64+d] f16
{
    __shared__ unsigned short SM[2][3 * 4096];  // per buf: Kh | Kl | V^T

    const int t = threadIdx.x;
    const int w = t >> 6, lane = t & 63;
    const int g = lane >> 5, l31 = lane & 31;
    const int bh = blockIdx.x;
    const int b = bh >> 4, h = bh & 15, q0 = blockIdx.y * 256;

    const size_t row0   = (size_t)b * SEQ;
    const size_t qcol   = (size_t)h * HD;
    const size_t kcol   = 1024 + qcol;
    const size_t vtbase = ((size_t)(b * HEADS + h)) * HD * SEQ;

    const int rl  = lane >> 3;                       // 0..7
    const int sw8 = ((lane & 7) ^ (rl & 7)) * 8;     // swizzled source chunk
    const int x7  = l31 & 7;                         // frag-read swizzle key

    auto stage = [&](int buf, int k0) {
#pragma unroll
        for (int inst = 0; inst < 2; ++inst) {
            const int r8 = w * 16 + inst * 8;
            const size_t gk = (row0 + k0 + r8 + rl) * QK_LD + kcol + sw8;
            const int lo = r8 * 64;
            dma16(QKh + gk, &SM[buf][lo]);
            dma16(QKl + gk, &SM[buf][4096 + lo]);
            const size_t gv = vtbase + (size_t)(r8 + rl) * SEQ + k0 + sw8;
            dma16(Vt + gv, &SM[buf][8192 + lo]);
        }
    };

    // Q B-frags direct from global: lane n = q-row, k(d) = ks*16 + g*8 + j.
    half8 bQh[2][4], bQl[2][4];
#pragma unroll
    for (int qs = 0; qs < 2; ++qs) {
        const size_t qr = (row0 + q0 + qs * 128 + w * 32 + l31) * QK_LD + qcol;
#pragma unroll
        for (int ks = 0; ks < 4; ++ks) {
            bQh[qs][ks] = *(const half8*)(QKh + qr + ks * 16 + g * 8);
            bQl[qs][ks] = *(const half8*)(QKl + qr + ks * 16 + g * 8);
        }
    }

    f32x16 o_acc[2][2];
#pragma unroll
    for (int qs = 0; qs < 2; ++qs)
#pragma unroll
        for (int mt = 0; mt < 2; ++mt)
#pragma unroll
            for (int r = 0; r < 16; ++r) o_acc[qs][mt][r] = 0.f;
    float m_r[2] = {-3.0e38f, -3.0e38f}, l_r[2] = {0.f, 0.f};

    stage(0, 0);
    const int NIT = SEQ / 64;
    for (int it = 0; it < NIT; ++it) {
        __syncthreads();
        const int cur = it & 1;
        if (it + 1 < NIT) stage(cur ^ 1, (it + 1) * 64);
        const unsigned short* Ks  = &SM[cur][0];
        const unsigned short* Ksl = &SM[cur][4096];
        const unsigned short* Vs  = &SM[cur][8192];

        // S^T = K.Q^T for BOTH q-sets (all MFMAs issued up front)
        f32x16 s[2][2];
#pragma unroll
        for (int qs = 0; qs < 2; ++qs)
#pragma unroll
            for (int kt = 0; kt < 2; ++kt)
#pragma unroll
                for (int r = 0; r < 16; ++r) s[qs][kt][r] = 0.f;
#pragma unroll
        for (int kt = 0; kt < 2; ++kt)
#pragma unroll
            for (int ks = 0; ks < 4; ++ks) {
                const int off = (kt * 32 + l31) * 64 + (((ks * 2 + g) ^ x7) * 8);
                half8 aKh = *(const half8*)&Ks[off];
                half8 aKl = *(const half8*)&Ksl[off];
#pragma unroll
                for (int qs = 0; qs < 2; ++qs) {
                    s[qs][kt] = __builtin_amdgcn_mfma_f32_32x32x16_f16(
                        aKh, bQh[qs][ks], s[qs][kt], 0, 0, 0);
                    s[qs][kt] = __builtin_amdgcn_mfma_f32_32x32x16_f16(
                        aKl, bQh[qs][ks], s[qs][kt], 0, 0, 0);
                    s[qs][kt] = __builtin_amdgcn_mfma_f32_32x32x16_f16(
                        aKh, bQl[qs][ks], s[qs][kt], 0, 0, 0);
                }
            }

        // Staggered: softmax(qs) then its PV, so PV(0) matrix work overlaps
        // softmax(1) VALU work.
#pragma unroll
        for (int qs = 0; qs < 2; ++qs) {
            float mx = s[qs][0][0];
#pragma unroll
            for (int kt = 0; kt < 2; ++kt)
#pragma unroll
                for (int r = 0; r < 16; ++r) mx = fmaxf(mx, s[qs][kt][r]);
            mx = fmaxf(mx, __shfl_xor(mx, 32));

            // Quiet fast path: no lane saw a new running max -> alpha == 1.
            if (__ballot(mx > m_r[qs])) {
                const float nm = fmaxf(m_r[qs], mx);
                const float al = EXP2F(m_r[qs] - nm);
                m_r[qs] = nm;
                l_r[qs] *= al;
#pragma unroll
                for (int mt = 0; mt < 2; ++mt)
#pragma unroll
                    for (int r = 0; r < 16; ++r) o_acc[qs][mt][r] *= al;
            }
            const float nm = m_r[qs];
            float rs = 0.f;
#pragma unroll
            for (int kt = 0; kt < 2; ++kt)
#pragma unroll
                for (int r = 0; r < 16; ++r) {
                    float pv = EXP2F(s[qs][kt][r] - nm);
                    s[qs][kt][r] = pv;
                    rs += pv;
                }
            rs += __shfl_xor(rs, 32);
            l_r[qs] += rs;

            // P: C-layout -> PV operand layout in registers (reg-quad swap
            // between lane pairs l <-> l^32).
            half8 bP[4];
#pragma unroll
            for (int kt = 0; kt < 2; ++kt)
#pragma unroll
                for (int ksl = 0; ksl < 2; ++ksl) {
                    const int base = ksl * 8;
                    unsigned int lo0 = pk2(s[qs][kt][base + 0], s[qs][kt][base + 1]);
                    unsigned int lo1 = pk2(s[qs][kt][base + 2], s[qs][kt][base + 3]);
                    unsigned int hi0 = pk2(s[qs][kt][base + 4], s[qs][kt][base + 5]);
                    unsigned int hi1 = pk2(s[qs][kt][base + 6], s[qs][kt][base + 7]);
                    unsigned int s0 = g ? lo0 : hi0;
                    unsigned int s1 = g ? lo1 : hi1;
                    unsigned int r0 = (unsigned int)__shfl_xor((int)s0, 32);
                    unsigned int r1 = (unsigned int)__shfl_xor((int)s1, 32);
                    union { unsigned int u[4]; half8 hv; } u;
                    u.u[0] = g ? r0 : lo0;
                    u.u[1] = g ? r1 : lo1;
                    u.u[2] = g ? hi0 : r0;
                    u.u[3] = g ? hi1 : r1;
                    bP[kt * 2 + ksl] = u.hv;
                }

            // O^T += V^T . P^T for this q-set
#pragma unroll
            for (int mt = 0; mt < 2; ++mt)
#pragma unroll
                for (int kk = 0; kk < 4; ++kk) {
                    const int off = (mt * 32 + l31) * 64 + (((kk * 2 + g) ^ x7) * 8);
                    half8 aV = *(const half8*)&Vs[off];
                    o_acc[qs][mt] = __builtin_amdgcn_mfma_f32_32x32x16_f16(
                        aV, bP[kk], o_acc[qs][mt], 0, 0, 0);
                }
        }
    }

    // Epilogue: O^T col = own q-row; rows d = (r&3)+8*(r>>2)+4g+32mt.
#pragma unroll
    for (int qs = 0; qs < 2; ++qs) {
        const float inv = 1.0f / l_r[qs];
        unsigned short* orow =
            Oc + (row0 + q0 + qs * 128 + w * 32 + l31) * DM + h * HD;
#pragma unroll
        for (int mt = 0; mt < 2; ++mt)
#pragma unroll
            for (int rq = 0; rq < 4; ++rq) {
                unsigned int w0 = pk2(o_acc[qs][mt][rq * 4 + 0] * inv,
                                      o_acc[qs][mt][rq * 4 + 1] * inv);
                unsigned int w1 = pk2(o_acc[qs][mt][rq * 4 + 2] * inv,
                                      o_acc[qs][mt][rq * 4 + 3] * inv);
                const int d0 = mt * 32 + rq * 8 + g * 4;
                uint2 pkd; pkd.x = w0; pkd.y = w1;
                *(uint2*)(orow + d0) = pkd;
            }
    }
}

// ---------------------------------------------------------------------------
extern "C" void kernel_launch(void* const* d_in, const int* in_sizes, int n_in,
                              void* d_out, int out_size, void* d_ws, size_t ws_size,
                              hipStream_t stream) {
    const float* x  = (const float*)d_in[0];
    const float* Wq = (const float*)d_in[1];
    const float* Wk = (const float*)d_in[2];
    const float* Wv = (const float*)d_in[3];
    const float* Wo = (const float*)d_in[4];
    float* out = (float*)d_out;

    char* ws = (char*)d_ws;
    const size_t SZ_TOK = (size_t)M_TOK * DM * 2;  // 16 MB f16 token matrix
    const size_t SZ_W   = (size_t)DM * DM * 2;     // 2 MB

    unsigned short* xh     = (unsigned short*)(ws);
    unsigned short* xl     = (unsigned short*)(ws + SZ_TOK);
    unsigned short* Wqkt_h = (unsigned short*)(ws + 2 * SZ_TOK);            // 4 MB
    unsigned short* Wqkt_l = (unsigned short*)(ws + 2 * SZ_TOK + 2 * SZ_W); // 4 MB
    unsigned short* Wvt    = (unsigned short*)(ws + 2 * SZ_TOK + 4 * SZ_W);
    unsigned short* Wot    = (unsigned short*)(ws + 2 * SZ_TOK + 5 * SZ_W);
    unsigned short* QKh    = (unsigned short*)(ws + 2 * SZ_TOK + 6 * SZ_W); // 32 MB
    unsigned short* QKl    = (unsigned short*)(ws + 4 * SZ_TOK + 6 * SZ_W); // 32 MB
    unsigned short* Vt_    = (unsigned short*)(ws + 6 * SZ_TOK + 6 * SZ_W); // 16 MB
    unsigned short* concat = xh;  // x dead after V projection

    dim3 blk(256);

    hipLaunchKernelGGL(split_cast, dim3(M_TOK * DM / (256 * 8)), blk, 0, stream,
                       x, xh, xl);
    hipLaunchKernelGGL(wtrans_all, dim3(DM / 64, DM / 64, 4), blk, 0, stream,
                       Wq, Wk, Wv, Wo, Wqkt_h, Wqkt_l, Wvt, Wot);

    // Merged Q|K projection: N = 2048, 3-pass split in, split out.
    hipLaunchKernelGGL(gemm_qk, dim3(QK_LD / 128, M_TOK / 128), blk, 0, stream,
                       xh, xl, Wqkt_h, Wqkt_l, QKh, QKl);
    hipLaunchKernelGGL((gemm_f16<3>), dim3(DM / 128, M_TOK / 128), blk, 0, stream,
                       xh, Wvt, Vt_, M_TOK, DM, DM);

    // Attention: grid (bh, qtile) so same-(b,h) blocks land on one XCD.
    hipLaunchKernelGGL(attn_f16, dim3(HEADS * BATCH, SEQ / 256), blk, 0, stream,
                       QKh, QKl, Vt_, concat);

    hipLaunchKernelGGL((gemm_f16<0>), dim3(DM / 128, M_TOK / 128), blk, 0, stream,
                       concat, Wot, out, M_TOK, DM, DM);
}